// Round 1
// baseline (1005.970 us; speedup 1.0000x reference)
//
#include <hip/hip_runtime.h>
#include <stdint.h>

// GNN_Layer on MI355X.
// Math: h = relu( xf@W^T + (a_ud@xf)@W_ud^T + (a_lr@xf)@W_lr^T + biases + hg@W_go^T + b_go )
// Restructured via associativity:  a@(xf@Wsel^T)  =>  one big bf16 MFMA GEMM
//   C[8192,512] = a_ud@Y_ud + a_lr@Y_lr + xf@W^T   (K = 8192+8192+512 = 16896 concatenated)
// with per-column row_add[j] = b+b_ud+b_lr+b_go + (W_go@h_g)[j] added in the epilogue.
//
// Workspace layout (requires ~44.1 MB):
//   xb      bf16[8192][512]            @ 0          (8,388,608 B)
//   Yt      bf16[512][16896]           @ 8,388,608  (17,301,504 B)  Yt[n][k]: k<8192 Y_ud^T, <16384 Y_lr^T, then W
//   Wb1     bf16[1536][512]            @ 25,690,112 (1,572,864 B)   rows: W_ud | W_lr | W_g
//   tg      f32[8192][512]             @ 27,262,976 (16,777,216 B)  mask[i]*relu(xf@W_g^T+b_g)
//   colsum  f32[512]                   @ 44,040,192
//   row_add f32[512]                   @ 44,042,240

typedef __attribute__((ext_vector_type(8))) short short8;   // 8 bf16 = 4 VGPRs (MFMA A/B frag)
typedef __attribute__((ext_vector_type(4))) float f32x4;    // MFMA C/D frag

typedef const __attribute__((address_space(1))) void* gas1_t;
typedef __attribute__((address_space(3))) void* las3_t;

__device__ __forceinline__ void gload16(const void* g, void* l) {
  // async global -> LDS, 16B per lane; LDS dest must be wavebase + lane*16 (it is, by construction)
  __builtin_amdgcn_global_load_lds((gas1_t)g, (las3_t)l, 16, 0, 0);
}

// pack two fp32 -> two bf16 by truncation (top halves), one v_perm_b32
__device__ __forceinline__ unsigned pack2t(float lo, float hi) {
  return __builtin_amdgcn_perm(__float_as_uint(hi), __float_as_uint(lo), 0x07060302u);
}

// round-to-nearest-even fp32 -> bf16
__device__ __forceinline__ unsigned f2bf_rne(float f) {
  unsigned u = __float_as_uint(f);
  return (u + 0x7FFFu + ((u >> 16) & 1u)) >> 16;
}
__device__ __forceinline__ unsigned pack2_rne(float lo, float hi) {
  return f2bf_rne(lo) | (f2bf_rne(hi) << 16);
}

// ---------------- K1: dtype conversion ----------------
// xb = bf16(x)  (524288 groups of 8);  W -> Yt tail; W_ud/W_lr/W_g -> Wb1 (32768 groups each)
__global__ __launch_bounds__(256) void k1_convert(
    const float* __restrict__ x, const float* __restrict__ W,
    const float* __restrict__ W_ud, const float* __restrict__ W_lr,
    const float* __restrict__ W_g,
    uint16_t* __restrict__ xb, uint16_t* __restrict__ Yt, uint16_t* __restrict__ Wb1)
{
  unsigned tid = blockIdx.x * 256u + threadIdx.x;   // 0..655359
  const float* src;
  uint16_t* dst;
  if (tid < 524288u) {
    src = x + (size_t)tid * 8;
    dst = xb + (size_t)tid * 8;
  } else {
    unsigned r = tid - 524288u;
    unsigned which = r >> 15;              // 0:W 1:W_ud 2:W_lr 3:W_g
    unsigned e8 = (r & 32767u) * 8;        // element offset in 512x512
    src = (which == 0 ? W : which == 1 ? W_ud : which == 2 ? W_lr : W_g) + e8;
    if (which == 0) {
      unsigned n = e8 >> 9, k = e8 & 511u;
      dst = Yt + (size_t)n * 16896 + 16384 + k;     // B-operand layout for the xf@W^T phase
    } else {
      dst = Wb1 + (size_t)(which - 1) * 262144 + e8;
    }
  }
  float4 v0 = ((const float4*)src)[0];
  float4 v1 = ((const float4*)src)[1];
  uint4 p;
  p.x = pack2_rne(v0.x, v0.y); p.y = pack2_rne(v0.z, v0.w);
  p.z = pack2_rne(v1.x, v1.y); p.w = pack2_rne(v1.z, v1.w);
  *(uint4*)dst = p;
}

// ---------------- K2: small GEMM  Z = xb @ Wb1^T  (M=8192, N=1536, K=512) ----------------
// groups by blockIdx.y: 0-3 -> Y_ud^T into Yt[:, 0:8192]; 4-7 -> Y_lr^T into Yt[:, 8192:16384];
// 8-11 -> tg = mask[i]*relu(Z + b_g)
__global__ __launch_bounds__(256) void k2_gemm1(
    const uint16_t* __restrict__ xb, const uint16_t* __restrict__ Wb1,
    const float* __restrict__ mask, const float* __restrict__ b_g,
    uint16_t* __restrict__ Yt, float* __restrict__ tg)
{
  __shared__ __align__(16) char smem[34816];   // staging 16KB; reused as 128x136 bf16 transpose buf
  char* const bufA = smem;
  char* const bufB = smem + 8192;

  const int t = threadIdx.x;
  const int i0 = blockIdx.x * 128;
  const int bn = blockIdx.y;
  const int n0 = bn * 128;                 // row base in Wb1 (0..1408)
  const int lane = t & 63, w = t >> 6;
  const int q = lane >> 4, l15 = lane & 15;
  const int wm = w >> 1, wn = w & 1;       // 2x2 waves, 64x64 tiles
  const int srow = t >> 2, spart = t & 3;  // staging: 4 threads x 16B per 64B row

  f32x4 acc[4][4] = {};

  const uint16_t* const aA0 = xb + (size_t)(i0 + srow) * 512 + spart * 8;
  const uint16_t* const aA1 = aA0 + (size_t)64 * 512;
  const uint16_t* const aB0 = Wb1 + (size_t)(n0 + srow) * 512 + spart * 8;
  const uint16_t* const aB1 = aB0 + (size_t)64 * 512;

  for (int s = 0; s < 16; ++s) {
    __syncthreads();
    const int kk = s << 5;
    gload16(aA0 + kk, bufA + t * 16);
    gload16(aA1 + kk, bufA + 4096 + t * 16);
    gload16(aB0 + kk, bufB + t * 16);
    gload16(aB1 + kk, bufB + 4096 + t * 16);
    __syncthreads();
    short8 af[4], bf[4];
#pragma unroll
    for (int mi = 0; mi < 4; ++mi)
      af[mi] = *(const short8*)(bufA + (wm * 64 + mi * 16 + l15) * 64 + q * 16);
#pragma unroll
    for (int ni = 0; ni < 4; ++ni)
      bf[ni] = *(const short8*)(bufB + (wn * 64 + ni * 16 + l15) * 64 + q * 16);
#pragma unroll
    for (int mi = 0; mi < 4; ++mi)
#pragma unroll
      for (int ni = 0; ni < 4; ++ni)
        acc[mi][ni] = __builtin_amdgcn_mfma_f32_16x16x32_bf16(af[mi], bf[ni], acc[mi][ni], 0, 0, 0);
  }
  __syncthreads();

  const int g = bn >> 2;            // 0: ud, 1: lr, 2: g-branch
  const int jb = (bn & 3) * 128;    // column base within group (0..511)

  if (g < 2) {
    // transpose 128x128 tile through LDS, emit bf16 rows of Yt (contiguous along k=i)
    uint16_t* T = (uint16_t*)smem;  // [128][136]
#pragma unroll
    for (int mi = 0; mi < 4; ++mi) {
#pragma unroll
      for (int ni = 0; ni < 4; ++ni) {
        int jl = wn * 64 + ni * 16 + l15;
#pragma unroll
        for (int r = 0; r < 4; ++r) {
          int il = wm * 64 + mi * 16 + q * 4 + r;
          T[jl * 136 + il] = (uint16_t)f2bf_rne(acc[mi][ni][r]);
        }
      }
    }
    __syncthreads();
    const int jl = t >> 1, half = t & 1;
    uint16_t* dst = Yt + (size_t)(jb + jl) * 16896 + (size_t)g * 8192 + i0 + half * 64;
    const uint16_t* srcT = T + jl * 136 + half * 64;
#pragma unroll
    for (int c = 0; c < 8; ++c)
      *(uint4*)(dst + c * 8) = *(const uint4*)(srcT + c * 8);
  } else {
    // tg[i][j] = mask[i] * relu(Z + b_g[j])
#pragma unroll
    for (int mi = 0; mi < 4; ++mi) {
#pragma unroll
      for (int ni = 0; ni < 4; ++ni) {
        int jl = jb + wn * 64 + ni * 16 + l15;
        float bg = b_g[jl];
#pragma unroll
        for (int r = 0; r < 4; ++r) {
          int il = i0 + wm * 64 + mi * 16 + q * 4 + r;
          float v = fmaxf(acc[mi][ni][r] + bg, 0.f) * mask[il];
          tg[(size_t)il * 512 + jl] = v;
        }
      }
    }
  }
}

// ---------------- K3: column partial-reduce of tg into colsum (atomic) ----------------
__global__ __launch_bounds__(256) void k3_reduce(const float* __restrict__ tg,
                                                 float* __restrict__ colsum)
{
  const int t = threadIdx.x;
  const int r0 = blockIdx.x * 64;
  float a0 = 0.f, a1 = 0.f;
  for (int r = 0; r < 64; ++r) {
    const float* row = tg + (size_t)(r0 + r) * 512;
    a0 += row[t];
    a1 += row[t + 256];
  }
  atomicAdd(&colsum[t], a0);
  atomicAdd(&colsum[t + 256], a1);
}

// ---------------- K4: h_g, row_add ----------------
__global__ __launch_bounds__(256) void k4_finalize(
    const float* __restrict__ colsum, const float* __restrict__ mask,
    const float* __restrict__ b, const float* __restrict__ b_ud,
    const float* __restrict__ b_lr, const float* __restrict__ W_go,
    const float* __restrict__ b_go,
    float* __restrict__ row_add, float* __restrict__ out_hg)
{
  __shared__ float red[256];
  __shared__ float hg[512];
  const int t = threadIdx.x;
  float s = 0.f;
  for (int k = t; k < 8192; k += 256) s += mask[k];
  red[t] = s;
  __syncthreads();
  for (int o = 128; o > 0; o >>= 1) {
    if (t < o) red[t] += red[t + o];
    __syncthreads();
  }
  const float n = red[0];
  for (int j = t; j < 512; j += 256) hg[j] = colsum[j] / n;
  __syncthreads();

  const int j0 = blockIdx.x * 64;
  const int jj = j0 + (t >> 2);
  const int seg = t & 3;
  const float4* wrow = (const float4*)(W_go + (size_t)jj * 512 + seg * 128);
  float p = 0.f;
#pragma unroll 4
  for (int c = 0; c < 32; ++c) {
    float4 wv = wrow[c];
    const float* h4 = &hg[seg * 128 + c * 4];
    p += wv.x * h4[0] + wv.y * h4[1] + wv.z * h4[2] + wv.w * h4[3];
  }
  p += __shfl_down(p, 2);
  p += __shfl_down(p, 1);
  if ((t & 3) == 0)
    row_add[jj] = b[jj] + b_ud[jj] + b_lr[jj] + b_go[jj] + p;
  if (t < 64) out_hg[j0 + t] = hg[j0 + t];
}

// ---------------- K5: big GEMM, K=16896 concatenated ----------------
// C[i,j] = sum_k A(i,k) * Yt[j][k];  A phases: a_ud (k<8192), a_lr (k<16384), x (k<16896)
// out = relu(C + row_add[j]).  BM=64 BN=128, 4 waves (2x2, 32x64 tiles), dbuf LDS, 1 barrier/step.
// A is fp32 in HBM: loaded as float4, packed to bf16 via v_perm (truncation) into LDS.
__global__ __launch_bounds__(256) void k5_gemm_big(
    const float* __restrict__ a_ud, const float* __restrict__ a_lr,
    const float* __restrict__ x, const uint16_t* __restrict__ Yt,
    const float* __restrict__ row_add, float* __restrict__ out)
{
  __shared__ __align__(16) char smem[26624];
  char* const bufA0 = smem;             // 64 rows * 80B (pad: 40 bf16 stride)
  char* const bufA1 = smem + 5120;
  char* const bufB0 = smem + 10240;     // 128 rows * 64B (tight: global_load_lds)
  char* const bufB1 = smem + 18432;

  const int t = threadIdx.x;
  const int i0 = blockIdx.x * 64;
  const int j0 = blockIdx.y * 128;
  const int lane = t & 63, w = t >> 6;
  const int q = lane >> 4, l15 = lane & 15;
  const int wm = w >> 1, wn = w & 1;        // 2x2 waves; wave tile 32(m) x 64(n)
  const int srow = t >> 2, spart = t & 3;

  f32x4 acc[2][4] = {};

  const size_t aoff_big = (size_t)(i0 + srow) * 8192 + spart * 8;
  const size_t aoff_x   = (size_t)(i0 + srow) * 512 + spart * 8;
  const uint16_t* const bsrc0 = Yt + (size_t)(j0 + srow) * 16896 + spart * 8;
  const uint16_t* const bsrc1 = bsrc0 + (size_t)64 * 16896;
  const int aw = srow * 80 + spart * 16;    // A LDS write offset

  float4 pA0, pA1;

  // prologue: stage step 0 into buf0
  {
    const float* asrc = a_ud + aoff_big;
    pA0 = ((const float4*)asrc)[0];
    pA1 = ((const float4*)asrc)[1];
    gload16(bsrc0, bufB0 + t * 16);
    gload16(bsrc1, bufB0 + 4096 + t * 16);
    uint4 pk;
    pk.x = pack2t(pA0.x, pA0.y); pk.y = pack2t(pA0.z, pA0.w);
    pk.z = pack2t(pA1.x, pA1.y); pk.w = pack2t(pA1.z, pA1.w);
    *(uint4*)(bufA0 + aw) = pk;
  }

  for (int s = 0; s < 528; ++s) {
    __syncthreads();   // buf[s&1] staged; buf[(s+1)&1] free to overwrite
    const int nxt = s + 1;
    const bool more = (nxt < 528);
    char* const cA = (s & 1) ? bufA1 : bufA0;
    char* const cB = (s & 1) ? bufB1 : bufB0;
    char* const nA = (s & 1) ? bufA0 : bufA1;
    char* const nB = (s & 1) ? bufB0 : bufB1;

    if (more) {
      const float* asrc;
      if (nxt < 256)      asrc = a_ud + aoff_big + (nxt << 5);
      else if (nxt < 512) asrc = a_lr + aoff_big + ((nxt - 256) << 5);
      else                asrc = x + aoff_x + ((nxt - 512) << 5);
      pA0 = ((const float4*)asrc)[0];
      pA1 = ((const float4*)asrc)[1];
      const int bk = nxt << 5;
      gload16(bsrc0 + bk, nB + t * 16);
      gload16(bsrc1 + bk, nB + 4096 + t * 16);
    }

    short8 af0 = *(const short8*)(cA + (wm * 32 + l15) * 80 + q * 16);
    short8 af1 = *(const short8*)(cA + (wm * 32 + 16 + l15) * 80 + q * 16);
    short8 bf0 = *(const short8*)(cB + (wn * 64 + l15) * 64 + q * 16);
    short8 bf1 = *(const short8*)(cB + (wn * 64 + 16 + l15) * 64 + q * 16);
    short8 bf2 = *(const short8*)(cB + (wn * 64 + 32 + l15) * 64 + q * 16);
    short8 bf3 = *(const short8*)(cB + (wn * 64 + 48 + l15) * 64 + q * 16);

    acc[0][0] = __builtin_amdgcn_mfma_f32_16x16x32_bf16(af0, bf0, acc[0][0], 0, 0, 0);
    acc[0][1] = __builtin_amdgcn_mfma_f32_16x16x32_bf16(af0, bf1, acc[0][1], 0, 0, 0);
    acc[0][2] = __builtin_amdgcn_mfma_f32_16x16x32_bf16(af0, bf2, acc[0][2], 0, 0, 0);
    acc[0][3] = __builtin_amdgcn_mfma_f32_16x16x32_bf16(af0, bf3, acc[0][3], 0, 0, 0);
    acc[1][0] = __builtin_amdgcn_mfma_f32_16x16x32_bf16(af1, bf0, acc[1][0], 0, 0, 0);
    acc[1][1] = __builtin_amdgcn_mfma_f32_16x16x32_bf16(af1, bf1, acc[1][1], 0, 0, 0);
    acc[1][2] = __builtin_amdgcn_mfma_f32_16x16x32_bf16(af1, bf2, acc[1][2], 0, 0, 0);
    acc[1][3] = __builtin_amdgcn_mfma_f32_16x16x32_bf16(af1, bf3, acc[1][3], 0, 0, 0);

    if (more) {
      uint4 pk;
      pk.x = pack2t(pA0.x, pA0.y); pk.y = pack2t(pA0.z, pA0.w);
      pk.z = pack2t(pA1.x, pA1.y); pk.w = pack2t(pA1.z, pA1.w);
      *(uint4*)(nA + aw) = pk;
    }
  }

  // epilogue: relu(acc + row_add[j])
#pragma unroll
  for (int ni = 0; ni < 4; ++ni) {
    const int jl = j0 + wn * 64 + ni * 16 + l15;
    const float ra = row_add[jl];
#pragma unroll
    for (int mi = 0; mi < 2; ++mi) {
#pragma unroll
      for (int r = 0; r < 4; ++r) {
        const int il = i0 + wm * 32 + mi * 16 + q * 4 + r;
        out[(size_t)il * 512 + jl] = fmaxf(acc[mi][ni][r] + ra, 0.f);
      }
    }
  }
}

extern "C" void kernel_launch(void* const* d_in, const int* in_sizes, int n_in,
                              void* d_out, int out_size, void* d_ws, size_t ws_size,
                              hipStream_t stream) {
  (void)in_sizes; (void)n_in; (void)out_size; (void)ws_size;
  const float* x    = (const float*)d_in[0];
  const float* mask = (const float*)d_in[1];
  const float* a_ud = (const float*)d_in[2];
  const float* a_lr = (const float*)d_in[3];
  const float* W    = (const float*)d_in[4];
  const float* b    = (const float*)d_in[5];
  const float* W_ud = (const float*)d_in[6];
  const float* b_ud = (const float*)d_in[7];
  const float* W_lr = (const float*)d_in[8];
  const float* b_lr = (const float*)d_in[9];
  const float* W_g  = (const float*)d_in[10];
  const float* b_g  = (const float*)d_in[11];
  const float* W_go = (const float*)d_in[12];
  const float* b_go = (const float*)d_in[13];
  float* out = (float*)d_out;

  char* ws = (char*)d_ws;
  uint16_t* xb     = (uint16_t*)(ws);
  uint16_t* Yt     = (uint16_t*)(ws + 8388608);
  uint16_t* Wb1    = (uint16_t*)(ws + 25690112);
  float*    tg     = (float*)(ws + 27262976);
  float*    colsum = (float*)(ws + 44040192);
  float*    rowadd = (float*)(ws + 44042240);

  hipMemsetAsync(colsum, 0, 512 * sizeof(float), stream);
  k1_convert<<<2560, 256, 0, stream>>>(x, W, W_ud, W_lr, W_g, xb, Yt, Wb1);
  k2_gemm1<<<dim3(64, 12), 256, 0, stream>>>(xb, Wb1, mask, b_g, Yt, tg);
  k3_reduce<<<128, 256, 0, stream>>>(tg, colsum);
  k4_finalize<<<8, 256, 0, stream>>>(colsum, mask, b, b_ud, b_lr, W_go, b_go,
                                     rowadd, out + 4194304);
  k5_gemm_big<<<dim3(128, 4), 256, 0, stream>>>(a_ud, a_lr, x, Yt, rowadd, out);
}

// Round 2
// 901.965 us; speedup vs baseline: 1.1153x; 1.1153x over previous
//
#include <hip/hip_runtime.h>
#include <stdint.h>

// GNN_Layer on MI355X.
// h = relu( xf@W^T + (a_ud@xf)@W_ud^T + (a_lr@xf)@W_lr^T + biases + hg@W_go^T + b_go )
// Restructured: C[8192,512] = a_ud@Y_ud + a_lr@Y_lr + xf@W^T  (K = 16896 concatenated),
// row_add[j] folds all biases + global branch; epilogue relu.
//
// R1 -> R2 changes (latency-bound fix):
//  * K5: BK 32->64 (half the barrier drains), split-K x2 (grid 512->1024, 3 blocks/CU
//    resident at 51.2KB LDS dbuf), XOR-swizzled B LDS layout + 144B-padded A rows
//    (both 2-way bank aliasing = free; was 8-way on B), partial-sum combine in K6.
//  * K3 folded into K2's g-branch epilogue (block-level reduce + atomicAdd colsum);
//    tg[8192][512] buffer eliminated.
//
// Workspace (44,044,288 B total == round-1 proven footprint):
//   xb      bf16[8192][512]   @ 0
//   Yt      bf16[512][16896]  @ 8,388,608    k<8192: Y_ud^T | <16384: Y_lr^T | tail: W
//   Wb1     bf16[1536][512]   @ 25,690,112   rows: W_ud | W_lr | W_g
//   colsum  f32[512]          @ 27,262,976
//   row_add f32[512]          @ 27,265,024
//   P1      f32[8192][512]    @ 27,267,072   split-K z=1 partial

typedef __attribute__((ext_vector_type(8))) short short8;   // 8 bf16 = 4 VGPRs
typedef __attribute__((ext_vector_type(4))) float f32x4;    // MFMA C/D frag

typedef const __attribute__((address_space(1))) void* gas1_t;
typedef __attribute__((address_space(3))) void* las3_t;

__device__ __forceinline__ void gload16(const void* g, void* l) {
  __builtin_amdgcn_global_load_lds((gas1_t)g, (las3_t)l, 16, 0, 0);
}

// pack two fp32 -> two bf16 by truncation (top halves), one v_perm_b32
__device__ __forceinline__ unsigned pack2t(float lo, float hi) {
  return __builtin_amdgcn_perm(__float_as_uint(hi), __float_as_uint(lo), 0x07060302u);
}

// round-to-nearest-even fp32 -> bf16
__device__ __forceinline__ unsigned f2bf_rne(float f) {
  unsigned u = __float_as_uint(f);
  return (u + 0x7FFFu + ((u >> 16) & 1u)) >> 16;
}
__device__ __forceinline__ unsigned pack2_rne(float lo, float hi) {
  return f2bf_rne(lo) | (f2bf_rne(hi) << 16);
}

// ---------------- K1: dtype conversion ----------------
__global__ __launch_bounds__(256) void k1_convert(
    const float* __restrict__ x, const float* __restrict__ W,
    const float* __restrict__ W_ud, const float* __restrict__ W_lr,
    const float* __restrict__ W_g,
    uint16_t* __restrict__ xb, uint16_t* __restrict__ Yt, uint16_t* __restrict__ Wb1)
{
  unsigned tid = blockIdx.x * 256u + threadIdx.x;   // 0..655359
  const float* src;
  uint16_t* dst;
  if (tid < 524288u) {
    src = x + (size_t)tid * 8;
    dst = xb + (size_t)tid * 8;
  } else {
    unsigned r = tid - 524288u;
    unsigned which = r >> 15;              // 0:W 1:W_ud 2:W_lr 3:W_g
    unsigned e8 = (r & 32767u) * 8;
    src = (which == 0 ? W : which == 1 ? W_ud : which == 2 ? W_lr : W_g) + e8;
    if (which == 0) {
      unsigned n = e8 >> 9, k = e8 & 511u;
      dst = Yt + (size_t)n * 16896 + 16384 + k;
    } else {
      dst = Wb1 + (size_t)(which - 1) * 262144 + e8;
    }
  }
  float4 v0 = ((const float4*)src)[0];
  float4 v1 = ((const float4*)src)[1];
  uint4 p;
  p.x = pack2_rne(v0.x, v0.y); p.y = pack2_rne(v0.z, v0.w);
  p.z = pack2_rne(v1.x, v1.y); p.w = pack2_rne(v1.z, v1.w);
  *(uint4*)dst = p;
}

// ---------------- K2: small GEMM  Z = xb @ Wb1^T  (M=8192, N=1536, K=512) ----------------
// blockIdx.y 0-3 -> Y_ud^T; 4-7 -> Y_lr^T; 8-11 -> colsum += mask*relu(Z+b_g) (fused K3)
__global__ __launch_bounds__(256) void k2_gemm1(
    const uint16_t* __restrict__ xb, const uint16_t* __restrict__ Wb1,
    const float* __restrict__ mask, const float* __restrict__ b_g,
    uint16_t* __restrict__ Yt, float* __restrict__ colsum)
{
  __shared__ __align__(16) char smem[34816];
  char* const bufA = smem;
  char* const bufB = smem + 8192;

  const int t = threadIdx.x;
  const int i0 = blockIdx.x * 128;
  const int bn = blockIdx.y;
  const int n0 = bn * 128;
  const int lane = t & 63, w = t >> 6;
  const int q = lane >> 4, l15 = lane & 15;
  const int wm = w >> 1, wn = w & 1;
  const int srow = t >> 2, spart = t & 3;

  f32x4 acc[4][4] = {};

  const uint16_t* const aA0 = xb + (size_t)(i0 + srow) * 512 + spart * 8;
  const uint16_t* const aA1 = aA0 + (size_t)64 * 512;
  const uint16_t* const aB0 = Wb1 + (size_t)(n0 + srow) * 512 + spart * 8;
  const uint16_t* const aB1 = aB0 + (size_t)64 * 512;

  for (int s = 0; s < 16; ++s) {
    __syncthreads();
    const int kk = s << 5;
    gload16(aA0 + kk, bufA + t * 16);
    gload16(aA1 + kk, bufA + 4096 + t * 16);
    gload16(aB0 + kk, bufB + t * 16);
    gload16(aB1 + kk, bufB + 4096 + t * 16);
    __syncthreads();
    short8 af[4], bf[4];
#pragma unroll
    for (int mi = 0; mi < 4; ++mi)
      af[mi] = *(const short8*)(bufA + (wm * 64 + mi * 16 + l15) * 64 + q * 16);
#pragma unroll
    for (int ni = 0; ni < 4; ++ni)
      bf[ni] = *(const short8*)(bufB + (wn * 64 + ni * 16 + l15) * 64 + q * 16);
#pragma unroll
    for (int mi = 0; mi < 4; ++mi)
#pragma unroll
      for (int ni = 0; ni < 4; ++ni)
        acc[mi][ni] = __builtin_amdgcn_mfma_f32_16x16x32_bf16(af[mi], bf[ni], acc[mi][ni], 0, 0, 0);
  }
  __syncthreads();

  const int g = bn >> 2;            // 0: ud, 1: lr, 2: g-branch
  const int jb = (bn & 3) * 128;

  if (g < 2) {
    // transpose 128x128 tile through LDS, emit bf16 rows of Yt
    uint16_t* T = (uint16_t*)smem;  // [128][136]
#pragma unroll
    for (int mi = 0; mi < 4; ++mi) {
#pragma unroll
      for (int ni = 0; ni < 4; ++ni) {
        int jl = wn * 64 + ni * 16 + l15;
#pragma unroll
        for (int r = 0; r < 4; ++r) {
          int il = wm * 64 + mi * 16 + q * 4 + r;
          T[jl * 136 + il] = (uint16_t)f2bf_rne(acc[mi][ni][r]);
        }
      }
    }
    __syncthreads();
    const int jl = t >> 1, half = t & 1;
    uint16_t* dst = Yt + (size_t)(jb + jl) * 16896 + (size_t)g * 8192 + i0 + half * 64;
    const uint16_t* srcT = T + jl * 136 + half * 64;
#pragma unroll
    for (int c = 0; c < 8; ++c)
      *(uint4*)(dst + c * 8) = *(const uint4*)(srcT + c * 8);
  } else {
    // fused global-branch reduction: colsum[j] += sum_i mask[i]*relu(Z[i][j]+b_g[j])
    float mk[4][4];
#pragma unroll
    for (int mi = 0; mi < 4; ++mi)
#pragma unroll
      for (int r = 0; r < 4; ++r)
        mk[mi][r] = mask[i0 + wm * 64 + mi * 16 + q * 4 + r];
#pragma unroll
    for (int ni = 0; ni < 4; ++ni) {
      const int jl = jb + wn * 64 + ni * 16 + l15;
      const float bg = b_g[jl];
      float p = 0.f;
#pragma unroll
      for (int mi = 0; mi < 4; ++mi)
#pragma unroll
        for (int r = 0; r < 4; ++r)
          p += fmaxf(acc[mi][ni][r] + bg, 0.f) * mk[mi][r];
      p += __shfl_xor(p, 16);
      p += __shfl_xor(p, 32);
      if (q == 0) atomicAdd(&colsum[jl], p);
    }
  }
}

// ---------------- K4: h_g, row_add ----------------
__global__ __launch_bounds__(256) void k4_finalize(
    const float* __restrict__ colsum, const float* __restrict__ mask,
    const float* __restrict__ b, const float* __restrict__ b_ud,
    const float* __restrict__ b_lr, const float* __restrict__ W_go,
    const float* __restrict__ b_go,
    float* __restrict__ row_add, float* __restrict__ out_hg)
{
  __shared__ float red[256];
  __shared__ float hg[512];
  const int t = threadIdx.x;
  float s = 0.f;
  for (int k = t; k < 8192; k += 256) s += mask[k];
  red[t] = s;
  __syncthreads();
  for (int o = 128; o > 0; o >>= 1) {
    if (t < o) red[t] += red[t + o];
    __syncthreads();
  }
  const float n = red[0];
  for (int j = t; j < 512; j += 256) hg[j] = colsum[j] / n;
  __syncthreads();

  const int j0 = blockIdx.x * 64;
  const int jj = j0 + (t >> 2);
  const int seg = t & 3;
  const float4* wrow = (const float4*)(W_go + (size_t)jj * 512 + seg * 128);
  float p = 0.f;
#pragma unroll 4
  for (int c = 0; c < 32; ++c) {
    float4 wv = wrow[c];
    const float* h4 = &hg[seg * 128 + c * 4];
    p += wv.x * h4[0] + wv.y * h4[1] + wv.z * h4[2] + wv.w * h4[3];
  }
  p += __shfl_down(p, 2);
  p += __shfl_down(p, 1);
  if ((t & 3) == 0)
    row_add[jj] = b[jj] + b_ud[jj] + b_lr[jj] + b_go[jj] + p;
  if (t < 64) out_hg[j0 + t] = hg[j0 + t];
}

// ---------------- K5: big GEMM, K=16896, split-K x2 ----------------
// BM=64 BN=128 BK=64; grid (128 i, 4 j, 2 z); 132 K-steps per block.
// A fp32 -> bf16 in-register pack -> LDS (144B padded rows, 2-way banks).
// B (Yt bf16) via global_load_lds with XOR chunk swizzle (2-way banks).
// z=0 -> out (plain store), z=1 -> P1; K6 combines.
__global__ __launch_bounds__(256) void k5_gemm_big(
    const float* __restrict__ a_ud, const float* __restrict__ a_lr,
    const float* __restrict__ x, const uint16_t* __restrict__ Yt,
    float* __restrict__ out, float* __restrict__ P1)
{
  __shared__ __align__(16) char smem[51200];
  char* const A0 = smem;             // 64 rows * 144B (128B data + 16B pad)
  char* const A1 = smem + 9216;
  char* const B0 = smem + 18432;     // 128 rows * 128B, chunk c stored at c^(row&7)
  char* const B1 = smem + 34816;

  const int t = threadIdx.x;
  const int i0 = blockIdx.x * 64;
  const int j0 = blockIdx.y * 128;
  const int z  = blockIdx.z;
  const int lane = t & 63;
  const int q = lane >> 4, l15 = lane & 15;
  const int w = t >> 6;
  const int wm = w >> 1, wn = w & 1;        // 2x2 waves; wave tile 32(m) x 64(n)

  // staging roles
  const int arow = t >> 2, aseg = t & 3;          // A: 64 rows x 4 segs of 16 floats
  const int brow = t >> 3;                        // B: rows (t>>3) + r*32
  const int bchunk = (t & 7) ^ ((t >> 3) & 7);    // xor-swizzled 16B chunk

  f32x4 acc[2][4] = {};
  const int kbase0 = z * 8448;

  float4 av0, av1, av2, av3;
  // A source for K-step base gk (phase select; boundaries are multiples of 64)
#define A_SRC(gk) ((gk) < 8192 \
    ? a_ud + (size_t)(i0 + arow) * 8192 + (gk) + aseg * 16 \
    : ((gk) < 16384 \
      ? a_lr + (size_t)(i0 + arow) * 8192 + ((gk) - 8192) + aseg * 16 \
      : x + (size_t)(i0 + arow) * 512 + ((gk) - 16384) + aseg * 16))

  // prologue: stage step 0 into A0/B0
  {
    const float* as = A_SRC(kbase0);
    av0 = ((const float4*)as)[0]; av1 = ((const float4*)as)[1];
    av2 = ((const float4*)as)[2]; av3 = ((const float4*)as)[3];
#pragma unroll
    for (int r = 0; r < 4; ++r) {
      const int jrow = r * 32 + brow;
      gload16(Yt + (size_t)(j0 + jrow) * 16896 + kbase0 + bchunk * 8,
              B0 + r * 4096 + t * 16);
    }
    uint4 p0, p1;
    p0.x = pack2t(av0.x, av0.y); p0.y = pack2t(av0.z, av0.w);
    p0.z = pack2t(av1.x, av1.y); p0.w = pack2t(av1.z, av1.w);
    p1.x = pack2t(av2.x, av2.y); p1.y = pack2t(av2.z, av2.w);
    p1.z = pack2t(av3.x, av3.y); p1.w = pack2t(av3.z, av3.w);
    *(uint4*)(A0 + arow * 144 + aseg * 32) = p0;
    *(uint4*)(A0 + arow * 144 + aseg * 32 + 16) = p1;
  }

  for (int s = 0; s < 132; ++s) {
    __syncthreads();
    const bool more = (s + 1 < 132);
    char* const cA = (s & 1) ? A1 : A0;
    char* const cB = (s & 1) ? B1 : B0;
    char* const nA = (s & 1) ? A0 : A1;
    char* const nB = (s & 1) ? B0 : B1;

    if (more) {
      const int gk = kbase0 + (s + 1) * 64;
      const float* as = A_SRC(gk);
      av0 = ((const float4*)as)[0]; av1 = ((const float4*)as)[1];
      av2 = ((const float4*)as)[2]; av3 = ((const float4*)as)[3];
#pragma unroll
      for (int r = 0; r < 4; ++r) {
        const int jrow = r * 32 + brow;
        gload16(Yt + (size_t)(j0 + jrow) * 16896 + gk + bchunk * 8,
                nB + r * 4096 + t * 16);
      }
    }

#pragma unroll
    for (int u = 0; u < 2; ++u) {
      const int c = u * 4 + q;                  // 16B chunk index within 128B row
      const int r0 = wm * 32 + l15;
      short8 af0 = *(const short8*)(cA + r0 * 144 + c * 16);
      short8 af1 = *(const short8*)(cA + (r0 + 16) * 144 + c * 16);
      short8 bfr[4];
#pragma unroll
      for (int ni = 0; ni < 4; ++ni) {
        const int jbr = wn * 64 + ni * 16 + l15;
        bfr[ni] = *(const short8*)(cB + jbr * 128 + (c ^ (jbr & 7)) * 16);
      }
#pragma unroll
      for (int ni = 0; ni < 4; ++ni) {
        acc[0][ni] = __builtin_amdgcn_mfma_f32_16x16x32_bf16(af0, bfr[ni], acc[0][ni], 0, 0, 0);
        acc[1][ni] = __builtin_amdgcn_mfma_f32_16x16x32_bf16(af1, bfr[ni], acc[1][ni], 0, 0, 0);
      }
    }

    if (more) {
      uint4 p0, p1;
      p0.x = pack2t(av0.x, av0.y); p0.y = pack2t(av0.z, av0.w);
      p0.z = pack2t(av1.x, av1.y); p0.w = pack2t(av1.z, av1.w);
      p1.x = pack2t(av2.x, av2.y); p1.y = pack2t(av2.z, av2.w);
      p1.z = pack2t(av3.x, av3.y); p1.w = pack2t(av3.z, av3.w);
      *(uint4*)(nA + arow * 144 + aseg * 32) = p0;
      *(uint4*)(nA + arow * 144 + aseg * 32 + 16) = p1;
    }
  }
#undef A_SRC

  float* dst = z ? P1 : out;
#pragma unroll
  for (int ni = 0; ni < 4; ++ni) {
    const int jl = j0 + wn * 64 + ni * 16 + l15;
#pragma unroll
    for (int mi = 0; mi < 2; ++mi)
#pragma unroll
      for (int r = 0; r < 4; ++r) {
        const int il = i0 + wm * 32 + mi * 16 + q * 4 + r;
        dst[(size_t)il * 512 + jl] = acc[mi][ni][r];
      }
  }
}

// ---------------- K6: combine split-K halves + row_add + relu ----------------
__global__ __launch_bounds__(256) void k6_combine(
    const float* __restrict__ P1, const float* __restrict__ row_add,
    float* __restrict__ out)
{
  const int idx = blockIdx.x * 256 + threadIdx.x;     // float4 index, 1048576 total
  const float4 a = ((const float4*)out)[idx];
  const float4 p = ((const float4*)P1)[idx];
  const float4 r = ((const float4*)row_add)[idx & 127];
  float4 o;
  o.x = fmaxf(a.x + p.x + r.x, 0.f);
  o.y = fmaxf(a.y + p.y + r.y, 0.f);
  o.z = fmaxf(a.z + p.z + r.z, 0.f);
  o.w = fmaxf(a.w + p.w + r.w, 0.f);
  ((float4*)out)[idx] = o;
}

extern "C" void kernel_launch(void* const* d_in, const int* in_sizes, int n_in,
                              void* d_out, int out_size, void* d_ws, size_t ws_size,
                              hipStream_t stream) {
  (void)in_sizes; (void)n_in; (void)out_size; (void)ws_size;
  const float* x    = (const float*)d_in[0];
  const float* mask = (const float*)d_in[1];
  const float* a_ud = (const float*)d_in[2];
  const float* a_lr = (const float*)d_in[3];
  const float* W    = (const float*)d_in[4];
  const float* b    = (const float*)d_in[5];
  const float* W_ud = (const float*)d_in[6];
  const float* b_ud = (const float*)d_in[7];
  const float* W_lr = (const float*)d_in[8];
  const float* b_lr = (const float*)d_in[9];
  const float* W_g  = (const float*)d_in[10];
  const float* b_g  = (const float*)d_in[11];
  const float* W_go = (const float*)d_in[12];
  const float* b_go = (const float*)d_in[13];
  float* out = (float*)d_out;

  char* ws = (char*)d_ws;
  uint16_t* xb     = (uint16_t*)(ws);
  uint16_t* Yt     = (uint16_t*)(ws + 8388608);
  uint16_t* Wb1    = (uint16_t*)(ws + 25690112);
  float*    colsum = (float*)(ws + 27262976);
  float*    rowadd = (float*)(ws + 27265024);
  float*    P1     = (float*)(ws + 27267072);

  hipMemsetAsync(colsum, 0, 512 * sizeof(float), stream);
  k1_convert<<<2560, 256, 0, stream>>>(x, W, W_ud, W_lr, W_g, xb, Yt, Wb1);
  k2_gemm1<<<dim3(64, 12), 256, 0, stream>>>(xb, Wb1, mask, b_g, Yt, colsum);
  k4_finalize<<<8, 256, 0, stream>>>(colsum, mask, b, b_ud, b_lr, W_go, b_go,
                                     rowadd, out + 4194304);
  k5_gemm_big<<<dim3(128, 4, 2), 256, 0, stream>>>(a_ud, a_lr, x, Yt, out, P1);
  k6_combine<<<4096, 256, 0, stream>>>(P1, rowadd, out);
}

// Round 3
// 863.925 us; speedup vs baseline: 1.1644x; 1.0440x over previous
//
#include <hip/hip_runtime.h>
#include <stdint.h>

// GNN_Layer on MI355X.
// h = relu( xf@W^T + (a_ud@xf)@W_ud^T + (a_lr@xf)@W_lr^T + biases + hg@W_go^T + b_go )
// Restructured: C[8192,512] = a_ud@Y_ud + a_lr@Y_lr + xf@W^T  (K = 16896 concatenated),
// row_add[j] folds all biases + global branch; epilogue relu.
//
// R2 -> R3 (occupancy/latency fix for k5):
//  * 128x128 tile, BK=32 (m97 sweet spot: same 16 MFMA/wave/step, 24 KB staged vs 32),
//  * split-K x4 (grid 64x4x4=1024), LDS 34.8 KB/block -> 4 resident blocks/CU,
//  * __launch_bounds__(256,4) pins VGPR<=128 (16 waves/CU; R2's VGPR=68 capped at 16
//    waves but LDS 51K allowed only 3 blocks),
//  * B swizzle fixed: chunk ^ ((row>>1)&3) (R2's row&7 left 4-way conflicts since 64B
//    rows alias banks mod 2); A rows 72B-padded (2-way = free).
//  * split-K partials P[0..2] need ws >= 77.6 MB; runtime gate (ws_size is constant
//    across calls) falls back to z=2 using only P[0] (proven 44 MB footprint).
//
// Workspace:
//   xb      bf16[8192][512]   @ 0
//   Yt      bf16[512][16896]  @ 8,388,608    k<8192: Y_ud^T | <16384: Y_lr^T | tail: W
//   Wb1     bf16[1536][512]   @ 25,690,112   rows: W_ud | W_lr | W_g
//   colsum  f32[512]          @ 27,262,976
//   row_add f32[512]          @ 27,265,024
//   P       f32[Z-1][8192][512] @ 27,267,072 split-K partials

typedef __attribute__((ext_vector_type(8))) short short8;   // 8 bf16 = 4 VGPRs
typedef __attribute__((ext_vector_type(4))) float f32x4;    // MFMA C/D frag

typedef const __attribute__((address_space(1))) void* gas1_t;
typedef __attribute__((address_space(3))) void* las3_t;

__device__ __forceinline__ void gload16(const void* g, void* l) {
  __builtin_amdgcn_global_load_lds((gas1_t)g, (las3_t)l, 16, 0, 0);
}

// pack two fp32 -> two bf16 by truncation (top halves), one v_perm_b32
__device__ __forceinline__ unsigned pack2t(float lo, float hi) {
  return __builtin_amdgcn_perm(__float_as_uint(hi), __float_as_uint(lo), 0x07060302u);
}

// round-to-nearest-even fp32 -> bf16
__device__ __forceinline__ unsigned f2bf_rne(float f) {
  unsigned u = __float_as_uint(f);
  return (u + 0x7FFFu + ((u >> 16) & 1u)) >> 16;
}
__device__ __forceinline__ unsigned pack2_rne(float lo, float hi) {
  return f2bf_rne(lo) | (f2bf_rne(hi) << 16);
}

// ---------------- K1: dtype conversion ----------------
__global__ __launch_bounds__(256) void k1_convert(
    const float* __restrict__ x, const float* __restrict__ W,
    const float* __restrict__ W_ud, const float* __restrict__ W_lr,
    const float* __restrict__ W_g,
    uint16_t* __restrict__ xb, uint16_t* __restrict__ Yt, uint16_t* __restrict__ Wb1)
{
  unsigned tid = blockIdx.x * 256u + threadIdx.x;   // 0..655359
  const float* src;
  uint16_t* dst;
  if (tid < 524288u) {
    src = x + (size_t)tid * 8;
    dst = xb + (size_t)tid * 8;
  } else {
    unsigned r = tid - 524288u;
    unsigned which = r >> 15;              // 0:W 1:W_ud 2:W_lr 3:W_g
    unsigned e8 = (r & 32767u) * 8;
    src = (which == 0 ? W : which == 1 ? W_ud : which == 2 ? W_lr : W_g) + e8;
    if (which == 0) {
      unsigned n = e8 >> 9, k = e8 & 511u;
      dst = Yt + (size_t)n * 16896 + 16384 + k;
    } else {
      dst = Wb1 + (size_t)(which - 1) * 262144 + e8;
    }
  }
  float4 v0 = ((const float4*)src)[0];
  float4 v1 = ((const float4*)src)[1];
  uint4 p;
  p.x = pack2_rne(v0.x, v0.y); p.y = pack2_rne(v0.z, v0.w);
  p.z = pack2_rne(v1.x, v1.y); p.w = pack2_rne(v1.z, v1.w);
  *(uint4*)dst = p;
}

// ---------------- K2: small GEMM  Z = xb @ Wb1^T  (M=8192, N=1536, K=512) ----------------
// blockIdx.y 0-3 -> Y_ud^T; 4-7 -> Y_lr^T; 8-11 -> colsum += mask*relu(Z+b_g)
__global__ __launch_bounds__(256) void k2_gemm1(
    const uint16_t* __restrict__ xb, const uint16_t* __restrict__ Wb1,
    const float* __restrict__ mask, const float* __restrict__ b_g,
    uint16_t* __restrict__ Yt, float* __restrict__ colsum)
{
  __shared__ __align__(16) char smem[34816];
  char* const bufA = smem;
  char* const bufB = smem + 8192;

  const int t = threadIdx.x;
  const int i0 = blockIdx.x * 128;
  const int bn = blockIdx.y;
  const int n0 = bn * 128;
  const int lane = t & 63, w = t >> 6;
  const int q = lane >> 4, l15 = lane & 15;
  const int wm = w >> 1, wn = w & 1;
  const int srow = t >> 2, spart = t & 3;

  f32x4 acc[4][4] = {};

  const uint16_t* const aA0 = xb + (size_t)(i0 + srow) * 512 + spart * 8;
  const uint16_t* const aA1 = aA0 + (size_t)64 * 512;
  const uint16_t* const aB0 = Wb1 + (size_t)(n0 + srow) * 512 + spart * 8;
  const uint16_t* const aB1 = aB0 + (size_t)64 * 512;

  for (int s = 0; s < 16; ++s) {
    __syncthreads();
    const int kk = s << 5;
    gload16(aA0 + kk, bufA + t * 16);
    gload16(aA1 + kk, bufA + 4096 + t * 16);
    gload16(aB0 + kk, bufB + t * 16);
    gload16(aB1 + kk, bufB + 4096 + t * 16);
    __syncthreads();
    short8 af[4], bf[4];
#pragma unroll
    for (int mi = 0; mi < 4; ++mi)
      af[mi] = *(const short8*)(bufA + (wm * 64 + mi * 16 + l15) * 64 + q * 16);
#pragma unroll
    for (int ni = 0; ni < 4; ++ni)
      bf[ni] = *(const short8*)(bufB + (wn * 64 + ni * 16 + l15) * 64 + q * 16);
#pragma unroll
    for (int mi = 0; mi < 4; ++mi)
#pragma unroll
      for (int ni = 0; ni < 4; ++ni)
        acc[mi][ni] = __builtin_amdgcn_mfma_f32_16x16x32_bf16(af[mi], bf[ni], acc[mi][ni], 0, 0, 0);
  }
  __syncthreads();

  const int g = bn >> 2;            // 0: ud, 1: lr, 2: g-branch
  const int jb = (bn & 3) * 128;

  if (g < 2) {
    // transpose 128x128 tile through LDS, emit bf16 rows of Yt
    uint16_t* T = (uint16_t*)smem;  // [128][136]
#pragma unroll
    for (int mi = 0; mi < 4; ++mi) {
#pragma unroll
      for (int ni = 0; ni < 4; ++ni) {
        int jl = wn * 64 + ni * 16 + l15;
#pragma unroll
        for (int r = 0; r < 4; ++r) {
          int il = wm * 64 + mi * 16 + q * 4 + r;
          T[jl * 136 + il] = (uint16_t)f2bf_rne(acc[mi][ni][r]);
        }
      }
    }
    __syncthreads();
    const int jl = t >> 1, half = t & 1;
    uint16_t* dst = Yt + (size_t)(jb + jl) * 16896 + (size_t)g * 8192 + i0 + half * 64;
    const uint16_t* srcT = T + jl * 136 + half * 64;
#pragma unroll
    for (int c = 0; c < 8; ++c)
      *(uint4*)(dst + c * 8) = *(const uint4*)(srcT + c * 8);
  } else {
    // fused global-branch reduction: colsum[j] += sum_i mask[i]*relu(Z[i][j]+b_g[j])
    float mk[4][4];
#pragma unroll
    for (int mi = 0; mi < 4; ++mi)
#pragma unroll
      for (int r = 0; r < 4; ++r)
        mk[mi][r] = mask[i0 + wm * 64 + mi * 16 + q * 4 + r];
#pragma unroll
    for (int ni = 0; ni < 4; ++ni) {
      const int jl = jb + wn * 64 + ni * 16 + l15;
      const float bg = b_g[jl];
      float p = 0.f;
#pragma unroll
      for (int mi = 0; mi < 4; ++mi)
#pragma unroll
        for (int r = 0; r < 4; ++r)
          p += fmaxf(acc[mi][ni][r] + bg, 0.f) * mk[mi][r];
      p += __shfl_xor(p, 16);
      p += __shfl_xor(p, 32);
      if (q == 0) atomicAdd(&colsum[jl], p);
    }
  }
}

// ---------------- K4: h_g, row_add ----------------
__global__ __launch_bounds__(256) void k4_finalize(
    const float* __restrict__ colsum, const float* __restrict__ mask,
    const float* __restrict__ b, const float* __restrict__ b_ud,
    const float* __restrict__ b_lr, const float* __restrict__ W_go,
    const float* __restrict__ b_go,
    float* __restrict__ row_add, float* __restrict__ out_hg)
{
  __shared__ float red[256];
  __shared__ float hg[512];
  const int t = threadIdx.x;
  float s = 0.f;
  for (int k = t; k < 8192; k += 256) s += mask[k];
  red[t] = s;
  __syncthreads();
  for (int o = 128; o > 0; o >>= 1) {
    if (t < o) red[t] += red[t + o];
    __syncthreads();
  }
  const float n = red[0];
  for (int j = t; j < 512; j += 256) hg[j] = colsum[j] / n;
  __syncthreads();

  const int j0 = blockIdx.x * 64;
  const int jj = j0 + (t >> 2);
  const int seg = t & 3;
  const float4* wrow = (const float4*)(W_go + (size_t)jj * 512 + seg * 128);
  float p = 0.f;
#pragma unroll 4
  for (int c = 0; c < 32; ++c) {
    float4 wv = wrow[c];
    const float* h4 = &hg[seg * 128 + c * 4];
    p += wv.x * h4[0] + wv.y * h4[1] + wv.z * h4[2] + wv.w * h4[3];
  }
  p += __shfl_down(p, 2);
  p += __shfl_down(p, 1);
  if ((t & 3) == 0)
    row_add[jj] = b[jj] + b_ud[jj] + b_lr[jj] + b_go[jj] + p;
  if (t < 64) out_hg[j0 + t] = hg[j0 + t];
}

// ---------------- K5: big GEMM, K=16896, split-K xZ ----------------
// BM=128 BN=128 BK=32; grid (64, 4, Z); nsteps = (16896/Z)/32 per block.
// A fp32 -> bf16 in-register pack -> LDS (72B-padded rows).
// B (Yt bf16) via global_load_lds with chunk ^ ((row>>1)&3) swizzle on the GLOBAL
// address (LDS dest must be wavebase + lane*16; scatter goes on the source side).
// z=0 -> out, z>0 -> P[(z-1)]; K6 combines.
__global__ __launch_bounds__(256, 4) void k5_gemm_big(
    const float* __restrict__ a_ud, const float* __restrict__ a_lr,
    const float* __restrict__ x, const uint16_t* __restrict__ Yt,
    float* __restrict__ out, float* __restrict__ P, int nsteps)
{
  __shared__ __align__(16) char smem[34816];
  char* const A0 = smem;              // 128 rows * 72B (64B data + 8B pad)
  char* const A1 = smem + 9216;
  char* const B0 = smem + 18432;      // 128 rows * 64B, chunk c at pos c^((row>>1)&3)
  char* const B1 = smem + 26624;

  const int t = threadIdx.x;
  const int i0 = blockIdx.x * 128;
  const int j0 = blockIdx.y * 128;
  const int z  = blockIdx.z;
  const int lane = t & 63;
  const int q = lane >> 4, l15 = lane & 15;
  const int w = t >> 6;
  const int wm = w >> 1, wn = w & 1;        // 2x2 waves; wave tile 64(m) x 64(n)

  // staging roles
  const int arow = t >> 1, ahalf = t & 1;   // A: 128 rows x 2 halves of 16 floats
  const int brow = t >> 2;                  // B: rows (t>>2) + r*64
  const int bchunk = (t & 3) ^ ((t >> 3) & 3);  // global-side swizzled 16B chunk

  f32x4 acc[4][4] = {};
  const int kbase0 = z * (nsteps << 5);

  float4 av0, av1, av2, av3;
#define A_SRC(gk) ((gk) < 8192 \
    ? a_ud + (size_t)(i0 + arow) * 8192 + (gk) + ahalf * 16 \
    : ((gk) < 16384 \
      ? a_lr + (size_t)(i0 + arow) * 8192 + ((gk) - 8192) + ahalf * 16 \
      : x + (size_t)(i0 + arow) * 512 + ((gk) - 16384) + ahalf * 16))

  // prologue: stage step 0 into A0/B0
  {
    const float* as = A_SRC(kbase0);
    av0 = ((const float4*)as)[0]; av1 = ((const float4*)as)[1];
    av2 = ((const float4*)as)[2]; av3 = ((const float4*)as)[3];
#pragma unroll
    for (int r = 0; r < 2; ++r)
      gload16(Yt + (size_t)(j0 + brow + r * 64) * 16896 + kbase0 + bchunk * 8,
              B0 + r * 4096 + t * 16);
    uint4 p0, p1;
    p0.x = pack2t(av0.x, av0.y); p0.y = pack2t(av0.z, av0.w);
    p0.z = pack2t(av1.x, av1.y); p0.w = pack2t(av1.z, av1.w);
    p1.x = pack2t(av2.x, av2.y); p1.y = pack2t(av2.z, av2.w);
    p1.z = pack2t(av3.x, av3.y); p1.w = pack2t(av3.z, av3.w);
    *(uint4*)(A0 + arow * 72 + ahalf * 32) = p0;
    *(uint4*)(A0 + arow * 72 + ahalf * 32 + 16) = p1;
  }

  for (int s = 0; s < nsteps; ++s) {
    __syncthreads();
    const bool more = (s + 1 < nsteps);
    char* const cA = (s & 1) ? A1 : A0;
    char* const cB = (s & 1) ? B1 : B0;
    char* const nA = (s & 1) ? A0 : A1;
    char* const nB = (s & 1) ? B0 : B1;

    if (more) {
      const int gk = kbase0 + ((s + 1) << 5);
      const float* as = A_SRC(gk);
      av0 = ((const float4*)as)[0]; av1 = ((const float4*)as)[1];
      av2 = ((const float4*)as)[2]; av3 = ((const float4*)as)[3];
#pragma unroll
      for (int r = 0; r < 2; ++r)
        gload16(Yt + (size_t)(j0 + brow + r * 64) * 16896 + gk + bchunk * 8,
                nB + r * 4096 + t * 16);
    }

    short8 af[4], bf[4];
#pragma unroll
    for (int mi = 0; mi < 4; ++mi)
      af[mi] = *(const short8*)(cA + (wm * 64 + mi * 16 + l15) * 72 + q * 16);
#pragma unroll
    for (int ni = 0; ni < 4; ++ni) {
      const int j = wn * 64 + ni * 16 + l15;
      bf[ni] = *(const short8*)(cB + j * 64 + ((q ^ ((j >> 1) & 3)) * 16));
    }
#pragma unroll
    for (int mi = 0; mi < 4; ++mi)
#pragma unroll
      for (int ni = 0; ni < 4; ++ni)
        acc[mi][ni] = __builtin_amdgcn_mfma_f32_16x16x32_bf16(af[mi], bf[ni], acc[mi][ni], 0, 0, 0);

    if (more) {
      uint4 p0, p1;
      p0.x = pack2t(av0.x, av0.y); p0.y = pack2t(av0.z, av0.w);
      p0.z = pack2t(av1.x, av1.y); p0.w = pack2t(av1.z, av1.w);
      p1.x = pack2t(av2.x, av2.y); p1.y = pack2t(av2.z, av2.w);
      p1.z = pack2t(av3.x, av3.y); p1.w = pack2t(av3.z, av3.w);
      *(uint4*)(nA + arow * 72 + ahalf * 32) = p0;
      *(uint4*)(nA + arow * 72 + ahalf * 32 + 16) = p1;
    }
  }
#undef A_SRC

  float* dst = z ? P + (size_t)(z - 1) * 4194304 : out;
#pragma unroll
  for (int ni = 0; ni < 4; ++ni) {
    const int jl = j0 + wn * 64 + ni * 16 + l15;
#pragma unroll
    for (int mi = 0; mi < 4; ++mi)
#pragma unroll
      for (int r = 0; r < 4; ++r) {
        const int il = i0 + wm * 64 + mi * 16 + q * 4 + r;
        dst[(size_t)il * 512 + jl] = acc[mi][ni][r];
      }
  }
}

// ---------------- K6: combine split-K partials + row_add + relu ----------------
__global__ __launch_bounds__(256) void k6_combine(
    const float* __restrict__ P, const float* __restrict__ row_add,
    float* __restrict__ out, int npart)
{
  const int idx = blockIdx.x * 256 + threadIdx.x;     // float4 index, 1048576 total
  float4 a = ((const float4*)out)[idx];
  for (int p = 0; p < npart; ++p) {
    const float4 v = ((const float4*)P)[(size_t)p * 1048576 + idx];
    a.x += v.x; a.y += v.y; a.z += v.z; a.w += v.w;
  }
  const float4 r = ((const float4*)row_add)[idx & 127];
  float4 o;
  o.x = fmaxf(a.x + r.x, 0.f);
  o.y = fmaxf(a.y + r.y, 0.f);
  o.z = fmaxf(a.z + r.z, 0.f);
  o.w = fmaxf(a.w + r.w, 0.f);
  ((float4*)out)[idx] = o;
}

extern "C" void kernel_launch(void* const* d_in, const int* in_sizes, int n_in,
                              void* d_out, int out_size, void* d_ws, size_t ws_size,
                              hipStream_t stream) {
  (void)in_sizes; (void)n_in; (void)out_size;
  const float* x    = (const float*)d_in[0];
  const float* mask = (const float*)d_in[1];
  const float* a_ud = (const float*)d_in[2];
  const float* a_lr = (const float*)d_in[3];
  const float* W    = (const float*)d_in[4];
  const float* b    = (const float*)d_in[5];
  const float* W_ud = (const float*)d_in[6];
  const float* b_ud = (const float*)d_in[7];
  const float* W_lr = (const float*)d_in[8];
  const float* b_lr = (const float*)d_in[9];
  const float* W_g  = (const float*)d_in[10];
  const float* b_g  = (const float*)d_in[11];
  const float* W_go = (const float*)d_in[12];
  const float* b_go = (const float*)d_in[13];
  float* out = (float*)d_out;

  char* ws = (char*)d_ws;
  uint16_t* xb     = (uint16_t*)(ws);
  uint16_t* Yt     = (uint16_t*)(ws + 8388608);
  uint16_t* Wb1    = (uint16_t*)(ws + 25690112);
  float*    colsum = (float*)(ws + 27262976);
  float*    rowadd = (float*)(ws + 27265024);
  float*    P      = (float*)(ws + 27267072);

  // ws gate: z=4 needs 3 partials (77.6 MB); fall back to z=2 (1 partial, 44 MB proven).
  const int Z = (ws_size >= 77598720u) ? 4 : 2;
  const int nsteps = (16896 / Z) / 32;

  hipMemsetAsync(colsum, 0, 512 * sizeof(float), stream);
  k1_convert<<<2560, 256, 0, stream>>>(x, W, W_ud, W_lr, W_g, xb, Yt, Wb1);
  k2_gemm1<<<dim3(64, 12), 256, 0, stream>>>(xb, Wb1, mask, b_g, Yt, colsum);
  k4_finalize<<<8, 256, 0, stream>>>(colsum, mask, b, b_ud, b_lr, W_go, b_go,
                                     rowadd, out + 4194304);
  k5_gemm_big<<<dim3(64, 4, Z), 256, 0, stream>>>(a_ud, a_lr, x, Yt, out, P, nsteps);
  k6_combine<<<4096, 256, 0, stream>>>(P, rowadd, out, Z - 1);
}